// Round 1
// 398.999 us; speedup vs baseline: 1.0321x; 1.0321x over previous
//
#include <hip/hip_runtime.h>

// Problem constants (static per reference)
#define NHEAD 8
#define NPOINT 4
#define NLVL 6
#define CDIM 256
#define BSZ 8
#define NQRY 4096
#define NVAL 10752

typedef __attribute__((ext_vector_type(8))) short short8;   // 8 bf16 = 4 VGPRs
typedef __attribute__((ext_vector_type(4))) float floatx4;  // MFMA acc
typedef __attribute__((ext_vector_type(2))) float float2v;  // packed f32 (v_pk_fma_f32)

__device__ __forceinline__ unsigned short f2bf(float f) {
    unsigned u = __float_as_uint(f);
    return (unsigned short)((u + 0x7FFFu + ((u >> 16) & 1u)) >> 16);  // RNE
}
__device__ __forceinline__ unsigned pack2(float a, float b) {
    return (unsigned)f2bf(a) | ((unsigned)f2bf(b) << 16);
}
__device__ __forceinline__ float blo(unsigned u) { return __uint_as_float(u << 16); }
__device__ __forceinline__ float bhi(unsigned u) { return __uint_as_float(u & 0xffff0000u); }

// ---- prep: W matrices -> bf16, transposed [N][256] -------------------------
// Wt rows: [0,256) = W_val^T; [256,832) = [W_off|W_attn]^T; [832,1088) = W_out^T
__global__ __launch_bounds__(256) void prep_w(
    const float* __restrict__ Wv, const float* __restrict__ Woff,
    const float* __restrict__ Wattn, const float* __restrict__ Wo,
    unsigned short* __restrict__ Wt)
{
    const int id = blockIdx.x * 256 + threadIdx.x;   // < 1088*256
    const int n = id >> 8, k = id & 255;
    float val;
    if (n < 256) val = Wv[k * 256 + n];
    else if (n < 832) {
        const int nn = n - 256;
        val = (nn < 384) ? Woff[k * 384 + nn] : Wattn[k * 192 + (nn - 384)];
    } else val = Wo[k * 256 + (n - 832)];
    Wt[id] = f2bf(val);
}

// ---- q = bf16(query + query_pos) ------------------------------------------
__global__ __launch_bounds__(256) void q_conv(
    const float* __restrict__ query, const float* __restrict__ qpos,
    unsigned short* __restrict__ qbf)
{
    const long i = ((long)blockIdx.x * 256 + threadIdx.x) * 4;
    const float4 a = *(const float4*)(query + i);
    const float4 b = *(const float4*)(qpos + i);
    ushort4 r;
    r.x = f2bf(a.x + b.x); r.y = f2bf(a.y + b.y);
    r.z = f2bf(a.z + b.z); r.w = f2bf(a.w + b.w);
    *(ushort4*)(qbf + i) = r;
}

// ---- bf16 MFMA GEMM: C[M,N] = A[M,256] @ Bt[N,256]^T + bias ---------------
// 512 thr = 8 waves; block tile 128 x BN; wave tile 64 x (BN/4).
// ABF: A is bf16 (else fp32, converted during staging).
// VTRANS: C -> bf16 [b][h][pos][32]. RESID: += resid fp32. SPLITB: bias2 at col>=384.
template<int BN, int ABF, int VTRANS, int RESID, int SPLITB>
__global__ __launch_bounds__(512) void gemm_mfma(
    const void* __restrict__ Av, const unsigned short* __restrict__ Bt,
    const float* __restrict__ bias, const float* __restrict__ bias2,
    const float* __restrict__ resid, void* __restrict__ Cv,
    int M, int Ntot)
{
    constexpr int BK = 32, BMt = 128, PAD = 8;   // LDS stride 40 bf16 = 80 B (2-way only)
    constexpr int WN = BN / 4, NT = WN / 16;
    __shared__ unsigned short As[BMt][BK + PAD];
    __shared__ unsigned short Bs[BN][BK + PAD];
    const int tid = threadIdx.x;
    const int bm = blockIdx.y * BMt;
    const int bcol = blockIdx.x * BN;
    const int wid = tid >> 6, lane = tid & 63;
    const int wm = (wid >> 2) * 64, wn = (wid & 3) * WN;
    const int lm = lane & 15, q8 = (lane >> 4) * 8;

    floatx4 acc[4][NT];
#pragma unroll
    for (int i = 0; i < 4; ++i)
#pragma unroll
        for (int j = 0; j < NT; ++j) acc[i][j] = (floatx4)0.0f;

    const int arow = tid >> 2, akp = (tid & 3) * 8;   // A: 8 elems/thread
    const int bn_ = tid >> 1, bkp = (tid & 1) * 16;   // B: 32 B/thread

    for (int k0 = 0; k0 < 256; k0 += BK) {
        if (ABF) {
            const unsigned short* A = (const unsigned short*)Av;
            uint4 v = *(const uint4*)(A + (long)(bm + arow) * 256 + k0 + akp);
            *(uint4*)&As[arow][akp] = v;
        } else {
            const float* A = (const float*)Av;
            const float* p = A + (long)(bm + arow) * 256 + k0 + akp;
            const float4 a = *(const float4*)p;
            const float4 b = *(const float4*)(p + 4);
            uint4 v;
            v.x = pack2(a.x, a.y); v.y = pack2(a.z, a.w);
            v.z = pack2(b.x, b.y); v.w = pack2(b.z, b.w);
            *(uint4*)&As[arow][akp] = v;
        }
        if (bn_ < BN) {
            const unsigned short* p = Bt + (long)(bcol + bn_) * 256 + k0 + bkp;
            uint4 v0 = *(const uint4*)p;
            uint4 v1 = *(const uint4*)(p + 8);
            *(uint4*)&Bs[bn_][bkp] = v0;
            *(uint4*)&Bs[bn_][bkp + 8] = v1;
        }
        __syncthreads();
        short8 af[4], bfr[NT];
#pragma unroll
        for (int i = 0; i < 4; ++i) af[i] = *(const short8*)&As[wm + i * 16 + lm][q8];
#pragma unroll
        for (int j = 0; j < NT; ++j) bfr[j] = *(const short8*)&Bs[wn + j * 16 + lm][q8];
#pragma unroll
        for (int i = 0; i < 4; ++i)
#pragma unroll
            for (int j = 0; j < NT; ++j)
                acc[i][j] = __builtin_amdgcn_mfma_f32_16x16x32_bf16(af[i], bfr[j], acc[i][j], 0, 0, 0);
        __syncthreads();
    }

    const int qrow = (lane >> 4) * 4;
#pragma unroll
    for (int j = 0; j < NT; ++j) {
        const int colg = bcol + wn + j * 16 + lm;
        const float bv = (SPLITB && colg >= 384) ? bias2[colg - 384] : bias[colg];
#pragma unroll
        for (int i = 0; i < 4; ++i) {
#pragma unroll
            for (int r = 0; r < 4; ++r) {
                const int rowl = wm + i * 16 + qrow + r;
                const int rowg = bm + rowl;
                float val = acc[i][j][r] + bv;
                if (VTRANS) {
                    // bf16 v in [b][h][pos][32]; 128 | NVAL so block is one batch
                    const int b = bm / NVAL;
                    const int pos = bm - b * NVAL + rowl;
                    const int h = colg >> 5, d = colg & 31;
                    ((unsigned short*)Cv)[(((long)(b * NHEAD + h)) * NVAL + pos) * 32 + d] = f2bf(val);
                } else {
                    if (RESID) val += resid[(long)rowg * 256 + colg];
                    ((float*)Cv)[(long)rowg * Ntot + colg] = val;
                }
            }
        }
    }
}

// ---- deformable sampling (wave per query, bf16 v, bf16 out) ----------------
// 256 thr = 4 waves = 4 queries. lane: head h = lane>>3, channels (lane&7)*4..+3.
// v: bf16 [b][h][pos][32]; oa row: [off(384) | attn(192)] fp32.
//
// Two-phase: (1) each lane computes softmax (8-lane shfl tree) + geometry for
// its 3 owned samples ONCE (was 8x redundant per head), stores 24-B records
// {w00,w01,w10,w11, pos*4 u16} in LDS; (2) all lanes gather + accumulate with
// packed-f32 math. Record stride 24 B -> 8 heads land on disjoint banks
// (broadcast within head), conflict-free ds_read_b64.
__global__ __launch_bounds__(256) void ms_sample4(
    const unsigned short* __restrict__ v,
    const float* __restrict__ oa,
    const float* __restrict__ refp,
    unsigned short* __restrict__ outi)
{
    __shared__ float s_rec[4][192 * 6];   // [wave][ (lp*8+h)*6 ] : 4x4608 B
    __shared__ float s_ref[4][12];
    const int tid = threadIdx.x;
    const int w = tid >> 6;
    const int lane = tid & 63;
    const int bq = blockIdx.x * 4 + w;
    const int b = bq >> 12;

    if (lane < 12) s_ref[w][lane] = refp[(long)bq * 12 + lane];
    __syncthreads();

    const int h = lane >> 3;
    const int li = lane & 7;
    const float* oarow = oa + (long)bq * 576;

    // ---- phase 1a: softmax over this head's 24 logits (3 per lane) --------
    const float* lgp = oarow + 384 + h * 24 + li * 3;
    const float lg0 = lgp[0], lg1 = lgp[1], lg2 = lgp[2];
    float mx = fmaxf(lg0, fmaxf(lg1, lg2));
    mx = fmaxf(mx, __shfl_xor(mx, 1));
    mx = fmaxf(mx, __shfl_xor(mx, 2));
    mx = fmaxf(mx, __shfl_xor(mx, 4));
    const float e0 = __expf(lg0 - mx);
    const float e1 = __expf(lg1 - mx);
    const float e2 = __expf(lg2 - mx);
    float den = e0 + e1 + e2;
    den += __shfl_xor(den, 1);
    den += __shfl_xor(den, 2);
    den += __shfl_xor(den, 4);
    const float inv = 1.0f / den;
    const float aw_[3] = {e0 * inv, e1 * inv, e2 * inv};

    // ---- phase 1b: geometry + fused weights for 3 owned samples -----------
    const float* offp = oarow + (h * 24 + li * 3) * 2;   // 8-B aligned
    const float2v od0 = *(const float2v*)(offp);
    const float2v od1 = *(const float2v*)(offp + 2);
    const float2v od2 = *(const float2v*)(offp + 4);

#pragma unroll
    for (int k = 0; k < 3; ++k) {
        const int lp = li * 3 + k;
        const int l = lp >> 2;
        const int sh = (l >= 3) ? (l - 3) : l;
        const int W = 64 >> sh;
        const int base = ((l >= 3) ? 5376 : 0)
                       + ((sh >= 1) ? 4096 : 0)
                       + ((sh >= 2) ? 1024 : 0);
        const float Wf = (float)W;
        const float ox = (k == 0) ? od0.x : (k == 1) ? od1.x : od2.x;
        const float oy = (k == 0) ? od0.y : (k == 1) ? od1.y : od2.y;
        const float rx = s_ref[w][l * 2 + 0];
        const float ry = s_ref[w][l * 2 + 1];
        const float x = rx * Wf + ox - 0.5f;   // == ((rx + ox/W)*W - 0.5), pow2
        const float y = ry * Wf + oy - 0.5f;
        const float xf = floorf(x), yf = floorf(y);
        const int x0 = (int)xf, y0 = (int)yf;
        const float lx = x - xf, ly = y - yf;
        const float wx0 = (x0 >= 0 && x0 < W)      ? (1.f - lx) : 0.f;
        const float wx1 = (x0 >= -1 && x0 < W - 1) ? lx         : 0.f;
        const float wy0 = (y0 >= 0 && y0 < W)      ? (1.f - ly) : 0.f;
        const float wy1 = (y0 >= -1 && y0 < W - 1) ? ly         : 0.f;
        const int x0c = min(max(x0, 0), W - 1);
        const int x1c = min(max(x0 + 1, 0), W - 1);
        const int y0c = min(max(y0, 0), W - 1);
        const int y1c = min(max(y0 + 1, 0), W - 1);
        const float aw = aw_[k];
        const unsigned p00 = (unsigned)(base + y0c * W + x0c);
        const unsigned p01 = (unsigned)(base + y0c * W + x1c);
        const unsigned p10 = (unsigned)(base + y1c * W + x0c);
        const unsigned p11 = (unsigned)(base + y1c * W + x1c);
        float* r = &s_rec[w][((lp << 3) + h) * 6];
        float2v wa, wb;
        wa.x = aw * wx0 * wy0; wa.y = aw * wx1 * wy0;
        wb.x = aw * wx0 * wy1; wb.y = aw * wx1 * wy1;
        *(float2v*)(r)     = wa;
        *(float2v*)(r + 2) = wb;
        uint2 pk;
        pk.x = p00 | (p01 << 16);
        pk.y = p10 | (p11 << 16);
        *(uint2*)(r + 4) = pk;
    }
    __syncthreads();

    // ---- phase 2: gather + accumulate (packed f32) ------------------------
    const unsigned short* vb = v + ((long)(b * NHEAD + h)) * NVAL * 32 + li * 4;
    float2v acc01 = {0.f, 0.f};   // channels c0,c1
    float2v acc23 = {0.f, 0.f};   // channels c2,c3
    const float* rp0 = &s_rec[w][h * 6];

#pragma unroll 4
    for (int lp = 0; lp < NLVL * NPOINT; ++lp) {
        const float* rp = rp0 + lp * 48;
        const float2v w01 = *(const float2v*)(rp);       // w00, w01
        const float2v w23 = *(const float2v*)(rp + 2);   // w10, w11
        const uint2 pp = *(const uint2*)(rp + 4);
        const uint2 u00 = *(const uint2*)(vb + ((pp.x & 0xffffu) << 5));
        const uint2 u01 = *(const uint2*)(vb + ((pp.x >> 16) << 5));
        const uint2 u10 = *(const uint2*)(vb + ((pp.y & 0xffffu) << 5));
        const uint2 u11 = *(const uint2*)(vb + ((pp.y >> 16) << 5));
        float2v c;
        c.x = blo(u00.x); c.y = bhi(u00.x); acc01 += w01.x * c;
        c.x = blo(u00.y); c.y = bhi(u00.y); acc23 += w01.x * c;
        c.x = blo(u01.x); c.y = bhi(u01.x); acc01 += w01.y * c;
        c.x = blo(u01.y); c.y = bhi(u01.y); acc23 += w01.y * c;
        c.x = blo(u10.x); c.y = bhi(u10.x); acc01 += w23.x * c;
        c.x = blo(u10.y); c.y = bhi(u10.y); acc23 += w23.x * c;
        c.x = blo(u11.x); c.y = bhi(u11.x); acc01 += w23.y * c;
        c.x = blo(u11.y); c.y = bhi(u11.y); acc23 += w23.y * c;
    }
    ushort4 o;
    o.x = f2bf(acc01.x); o.y = f2bf(acc01.y);
    o.z = f2bf(acc23.x); o.w = f2bf(acc23.y);
    *(ushort4*)(outi + (long)bq * CDIM + lane * 4) = o;   // channel = lane*4
}

// ---------------- launch ---------------------------------------------------
extern "C" void kernel_launch(void* const* d_in, const int* in_sizes, int n_in,
                              void* d_out, int out_size, void* d_ws, size_t ws_size,
                              hipStream_t stream) {
    const float* query     = (const float*)d_in[0];
    const float* query_pos = (const float*)d_in[1];
    const float* value     = (const float*)d_in[2];
    const float* refp      = (const float*)d_in[3];
    // d_in[4] = spatial_shapes (static, hard-coded)
    const float* W_off  = (const float*)d_in[5];
    const float* b_off  = (const float*)d_in[6];
    const float* W_attn = (const float*)d_in[7];
    const float* b_attn = (const float*)d_in[8];
    const float* W_val  = (const float*)d_in[9];
    const float* b_val  = (const float*)d_in[10];
    const float* W_out  = (const float*)d_in[11];
    const float* b_out  = (const float*)d_in[12];
    float* out = (float*)d_out;

    // workspace: all bf16 buffers as ushort
    unsigned short* v_bf = (unsigned short*)d_ws;            // 86016*256 bf16 [b][h][pos][32]
    unsigned short* q_bf = v_bf + (long)86016 * 256;         // 32768*256 bf16
    unsigned short* Wt   = q_bf + (long)32768 * 256;         // 1088*256 bf16 (transposed W's)
    float* oa_ws = (float*)(Wt + (long)1088 * 256);          // 32768*576 fp32 [off|attn]
    unsigned short* i_bf = (unsigned short*)(oa_ws + (long)32768 * 576);  // 32768*256 bf16

    const int MV = BSZ * NVAL;   // 86016
    const int MQ = BSZ * NQRY;   // 32768

    // W -> bf16 transposed
    prep_w<<<1088, 256, 0, stream>>>(W_val, W_off, W_attn, W_out, Wt);
    // q = bf16(query + query_pos)
    q_conv<<<(MQ * CDIM / 4) / 256, 256, 0, stream>>>(query, query_pos, q_bf);
    // v = value @ W_val + b_val -> bf16 [b][h][pos][32]   (A fp32 in-kernel cvt)
    gemm_mfma<256, 0, 1, 0, 0><<<dim3(1, MV / 128), 512, 0, stream>>>(
        value, Wt, b_val, nullptr, nullptr, v_bf, MV, 256);
    // [off|attn] = q @ [W_off|W_attn] + [b_off|b_attn]  (fp32 out, N=576)
    gemm_mfma<192, 1, 0, 0, 1><<<dim3(3, MQ / 128), 512, 0, stream>>>(
        q_bf, Wt + (long)256 * 256, b_off, b_attn, nullptr, oa_ws, MQ, 576);
    // deformable sampling -> interm bf16
    ms_sample4<<<MQ / 4, 256, 0, stream>>>(v_bf, oa_ws, refp, i_bf);
    // out = interm @ W_out + b_out + query
    gemm_mfma<256, 1, 0, 1, 0><<<dim3(1, MQ / 128), 512, 0, stream>>>(
        i_bf, Wt + (long)832 * 256, b_out, nullptr, query, out, MQ, 256);
}

// Round 2
// 394.040 us; speedup vs baseline: 1.0450x; 1.0126x over previous
//
#include <hip/hip_runtime.h>

// Problem constants (static per reference)
#define NHEAD 8
#define NPOINT 4
#define NLVL 6
#define CDIM 256
#define BSZ 8
#define NQRY 4096
#define NVAL 10752

typedef __attribute__((ext_vector_type(8))) short short8;   // 8 bf16 = 4 VGPRs
typedef __attribute__((ext_vector_type(4))) float floatx4;  // MFMA acc
typedef __attribute__((ext_vector_type(2))) float float2v;  // packed f32 (v_pk_fma_f32)

__device__ __forceinline__ unsigned short f2bf(float f) {
    unsigned u = __float_as_uint(f);
    return (unsigned short)((u + 0x7FFFu + ((u >> 16) & 1u)) >> 16);  // RNE
}
__device__ __forceinline__ unsigned pack2(float a, float b) {
    return (unsigned)f2bf(a) | ((unsigned)f2bf(b) << 16);
}
__device__ __forceinline__ float blo(unsigned u) { return __uint_as_float(u << 16); }
__device__ __forceinline__ float bhi(unsigned u) { return __uint_as_float(u & 0xffff0000u); }

// ---- prep: W matrices -> bf16, transposed [N][256] -------------------------
// Wt rows: [0,256) = W_val^T; [256,832) = [W_off|W_attn]^T; [832,1088) = W_out^T
__global__ __launch_bounds__(256) void prep_w(
    const float* __restrict__ Wv, const float* __restrict__ Woff,
    const float* __restrict__ Wattn, const float* __restrict__ Wo,
    unsigned short* __restrict__ Wt)
{
    const int id = blockIdx.x * 256 + threadIdx.x;   // < 1088*256
    const int n = id >> 8, k = id & 255;
    float val;
    if (n < 256) val = Wv[k * 256 + n];
    else if (n < 832) {
        const int nn = n - 256;
        val = (nn < 384) ? Woff[k * 384 + nn] : Wattn[k * 192 + (nn - 384)];
    } else val = Wo[k * 256 + (n - 832)];
    Wt[id] = f2bf(val);
}

// ---- q = bf16(query + query_pos) ------------------------------------------
__global__ __launch_bounds__(256) void q_conv(
    const float* __restrict__ query, const float* __restrict__ qpos,
    unsigned short* __restrict__ qbf)
{
    const long i = ((long)blockIdx.x * 256 + threadIdx.x) * 4;
    const float4 a = *(const float4*)(query + i);
    const float4 b = *(const float4*)(qpos + i);
    ushort4 r;
    r.x = f2bf(a.x + b.x); r.y = f2bf(a.y + b.y);
    r.z = f2bf(a.z + b.z); r.w = f2bf(a.w + b.w);
    *(ushort4*)(qbf + i) = r;
}

// ---- bf16 MFMA GEMM: C[M,N] = A[M,256] @ Bt[N,256]^T + bias ---------------
// 512 thr = 8 waves; block tile 128 x BN; wave tile 64 x (BN/4).
// ABF: A is bf16 (else fp32, converted during staging).
// VTRANS: C -> bf16 [b][h][pos][32]. RESID: += resid fp32. SPLITB: bias2 at col>=384.
template<int BN, int ABF, int VTRANS, int RESID, int SPLITB>
__global__ __launch_bounds__(512) void gemm_mfma(
    const void* __restrict__ Av, const unsigned short* __restrict__ Bt,
    const float* __restrict__ bias, const float* __restrict__ bias2,
    const float* __restrict__ resid, void* __restrict__ Cv,
    int M, int Ntot)
{
    constexpr int BK = 32, BMt = 128, PAD = 8;   // LDS stride 40 bf16 = 80 B (2-way only)
    constexpr int WN = BN / 4, NT = WN / 16;
    __shared__ unsigned short As[BMt][BK + PAD];
    __shared__ unsigned short Bs[BN][BK + PAD];
    const int tid = threadIdx.x;
    const int bm = blockIdx.y * BMt;
    const int bcol = blockIdx.x * BN;
    const int wid = tid >> 6, lane = tid & 63;
    const int wm = (wid >> 2) * 64, wn = (wid & 3) * WN;
    const int lm = lane & 15, q8 = (lane >> 4) * 8;

    floatx4 acc[4][NT];
#pragma unroll
    for (int i = 0; i < 4; ++i)
#pragma unroll
        for (int j = 0; j < NT; ++j) acc[i][j] = (floatx4)0.0f;

    const int arow = tid >> 2, akp = (tid & 3) * 8;   // A: 8 elems/thread
    const int bn_ = tid >> 1, bkp = (tid & 1) * 16;   // B: 32 B/thread

    for (int k0 = 0; k0 < 256; k0 += BK) {
        if (ABF) {
            const unsigned short* A = (const unsigned short*)Av;
            uint4 v = *(const uint4*)(A + (long)(bm + arow) * 256 + k0 + akp);
            *(uint4*)&As[arow][akp] = v;
        } else {
            const float* A = (const float*)Av;
            const float* p = A + (long)(bm + arow) * 256 + k0 + akp;
            const float4 a = *(const float4*)p;
            const float4 b = *(const float4*)(p + 4);
            uint4 v;
            v.x = pack2(a.x, a.y); v.y = pack2(a.z, a.w);
            v.z = pack2(b.x, b.y); v.w = pack2(b.z, b.w);
            *(uint4*)&As[arow][akp] = v;
        }
        if (bn_ < BN) {
            const unsigned short* p = Bt + (long)(bcol + bn_) * 256 + k0 + bkp;
            uint4 v0 = *(const uint4*)p;
            uint4 v1 = *(const uint4*)(p + 8);
            *(uint4*)&Bs[bn_][bkp] = v0;
            *(uint4*)&Bs[bn_][bkp + 8] = v1;
        }
        __syncthreads();
        short8 af[4], bfr[NT];
#pragma unroll
        for (int i = 0; i < 4; ++i) af[i] = *(const short8*)&As[wm + i * 16 + lm][q8];
#pragma unroll
        for (int j = 0; j < NT; ++j) bfr[j] = *(const short8*)&Bs[wn + j * 16 + lm][q8];
#pragma unroll
        for (int i = 0; i < 4; ++i)
#pragma unroll
            for (int j = 0; j < NT; ++j)
                acc[i][j] = __builtin_amdgcn_mfma_f32_16x16x32_bf16(af[i], bfr[j], acc[i][j], 0, 0, 0);
        __syncthreads();
    }

    const int qrow = (lane >> 4) * 4;
#pragma unroll
    for (int j = 0; j < NT; ++j) {
        const int colg = bcol + wn + j * 16 + lm;
        const float bv = (SPLITB && colg >= 384) ? bias2[colg - 384] : bias[colg];
#pragma unroll
        for (int i = 0; i < 4; ++i) {
#pragma unroll
            for (int r = 0; r < 4; ++r) {
                const int rowl = wm + i * 16 + qrow + r;
                const int rowg = bm + rowl;
                float val = acc[i][j][r] + bv;
                if (VTRANS) {
                    // bf16 v in [b][h][pos][32]; 128 | NVAL so block is one batch
                    const int b = bm / NVAL;
                    const int pos = bm - b * NVAL + rowl;
                    const int h = colg >> 5, d = colg & 31;
                    ((unsigned short*)Cv)[(((long)(b * NHEAD + h)) * NVAL + pos) * 32 + d] = f2bf(val);
                } else {
                    if (RESID) val += resid[(long)rowg * 256 + colg];
                    ((float*)Cv)[(long)rowg * Ntot + colg] = val;
                }
            }
        }
    }
}

// ---- deformable sampling (wave per query, bf16 v, bf16 out) ----------------
// 256 thr = 4 waves = 4 queries. lane: head h = lane>>3, li = lane&7.
// v: bf16 [b][h][pos][32]; oa row: [off(384) | attn(192)] fp32.
//
// Two-phase. Phase 1: each lane owns 3 samples of its head; softmax via 8-lane
// shfl tree; per sample compute geometry ONCE and store a 24-B record
// {w0l,w1l,w0r,w1r, byteoff_row0, byteoff_row1} in LDS. The two x-corners of a
// bilinear row are adjacent 64-B blocks -> one 128-B contiguous region starting
// at xb=clamp(x0,0,W-2); corner weights re-assigned so the extra column gets 0.
// Phase 2: per (lp,row) ONE dwordx4 gather (8 lanes x 16B = 128B: lanes 0-3 =
// left corner ch li*8..+7, lanes 4-7 = right corner). Halves VMEM instrs vs
// 4x dwordx2. Corner-side partials summed at the end via shfl_xor(4).
__global__ __launch_bounds__(256) void ms_sample4(
    const unsigned short* __restrict__ v,
    const float* __restrict__ oa,
    const float* __restrict__ refp,
    unsigned short* __restrict__ outi)
{
    __shared__ float s_rec[4][192 * 6];   // [wave][ (lp*8+h)*6 ] : 4x4608 B
    __shared__ float s_ref[4][12];
    const int tid = threadIdx.x;
    const int w = tid >> 6;
    const int lane = tid & 63;
    const int bq = blockIdx.x * 4 + w;
    const int b = bq >> 12;

    if (lane < 12) s_ref[w][lane] = refp[(long)bq * 12 + lane];
    __syncthreads();

    const int h = lane >> 3;
    const int li = lane & 7;
    const float* oarow = oa + (long)bq * 576;

    // ---- phase 1a: softmax over this head's 24 logits (3 per lane) --------
    const float* lgp = oarow + 384 + h * 24 + li * 3;
    const float lg0 = lgp[0], lg1 = lgp[1], lg2 = lgp[2];
    float mx = fmaxf(lg0, fmaxf(lg1, lg2));
    mx = fmaxf(mx, __shfl_xor(mx, 1));
    mx = fmaxf(mx, __shfl_xor(mx, 2));
    mx = fmaxf(mx, __shfl_xor(mx, 4));
    const float e0 = __expf(lg0 - mx);
    const float e1 = __expf(lg1 - mx);
    const float e2 = __expf(lg2 - mx);
    float den = e0 + e1 + e2;
    den += __shfl_xor(den, 1);
    den += __shfl_xor(den, 2);
    den += __shfl_xor(den, 4);
    const float inv = 1.0f / den;
    const float aw_[3] = {e0 * inv, e1 * inv, e2 * inv};

    // ---- phase 1b: geometry + fused weights for 3 owned samples -----------
    const float* offp = oarow + (h * 24 + li * 3) * 2;   // 8-B aligned
    const float2v od0 = *(const float2v*)(offp);
    const float2v od1 = *(const float2v*)(offp + 2);
    const float2v od2 = *(const float2v*)(offp + 4);

#pragma unroll
    for (int k = 0; k < 3; ++k) {
        const int lp = li * 3 + k;
        const int l = lp >> 2;
        const int sh = (l >= 3) ? (l - 3) : l;
        const int W = 64 >> sh;
        const int base = ((l >= 3) ? 5376 : 0)
                       + ((sh >= 1) ? 4096 : 0)
                       + ((sh >= 2) ? 1024 : 0);
        const float Wf = (float)W;
        const float ox = (k == 0) ? od0.x : (k == 1) ? od1.x : od2.x;
        const float oy = (k == 0) ? od0.y : (k == 1) ? od1.y : od2.y;
        const float rx = s_ref[w][l * 2 + 0];
        const float ry = s_ref[w][l * 2 + 1];
        const float x = rx * Wf + ox - 0.5f;   // == ((rx + ox/W)*W - 0.5), pow2
        const float y = ry * Wf + oy - 0.5f;
        const float xf = floorf(x), yf = floorf(y);
        const int x0 = (int)xf, y0 = (int)yf;
        const float lx = x - xf, ly = y - yf;
        const float wx0 = (x0 >= 0 && x0 < W)      ? (1.f - lx) : 0.f;
        const float wx1 = (x0 >= -1 && x0 < W - 1) ? lx         : 0.f;
        const float wy0 = (y0 >= 0 && y0 < W)      ? (1.f - ly) : 0.f;
        const float wy1 = (y0 >= -1 && y0 < W - 1) ? ly         : 0.f;
        const int y0c = min(max(y0, 0), W - 1);
        const int y1c = min(max(y0 + 1, 0), W - 1);
        // x: load 128-B region [xb, xb+1]; re-assign corner weights so the
        // padded column carries weight 0 (OOB corners have wx==0 already).
        const int xb = min(max(x0, 0), W - 2);
        const float wl = (xb == x0) ? wx0 : ((xb == x0 + 1) ? wx1 : 0.f);
        const float wr = (xb == x0) ? wx1 : ((xb == x0 - 1) ? wx0 : 0.f);
        const float aw = aw_[k];
        const float awl = aw * wl, awr = aw * wr;
        float* r = &s_rec[w][((lp << 3) + h) * 6];
        float2v wlv, wrv;
        wlv.x = awl * wy0; wlv.y = awl * wy1;   // (row0, row1) left corner
        wrv.x = awr * wy0; wrv.y = awr * wy1;   // (row0, row1) right corner
        *(float2v*)(r)     = wlv;
        *(float2v*)(r + 2) = wrv;
        uint2 pk;
        pk.x = (unsigned)(base + y0c * W + xb) * 64u;   // byte offset, row0
        pk.y = (unsigned)(base + y1c * W + xb) * 64u;   // byte offset, row1
        *(uint2*)(r + 4) = pk;
    }
    __syncthreads();

    // ---- phase 2: gather + accumulate (packed f32) ------------------------
    // lane carries 8 channels [(li&3)*8 .. +7] of ONE corner side (li<4 left).
    const unsigned lane_base =
        (unsigned)((b * NHEAD + h) * NVAL) * 64u + (unsigned)li * 16u;
    const char* vbase = (const char*)v;
    const int sel = (li >> 2) * 2;            // weight pair: 0=left, 2=right
    const float* rp0 = &s_rec[w][h * 6];
    float2v a01 = {0.f, 0.f}, a23 = {0.f, 0.f};
    float2v a45 = {0.f, 0.f}, a67 = {0.f, 0.f};

#pragma unroll 8
    for (int lp = 0; lp < NLVL * NPOINT; ++lp) {
        const float* rp = rp0 + lp * 48;
        const float2v wv = *(const float2v*)(rp + sel);   // (w_row0, w_row1)
        const uint2 off = *(const uint2*)(rp + 4);
        const uint4 u0 = *(const uint4*)(vbase + (lane_base + off.x));
        const uint4 u1 = *(const uint4*)(vbase + (lane_base + off.y));
        float2v c;
        c.x = blo(u0.x); c.y = bhi(u0.x); a01 += wv.x * c;
        c.x = blo(u0.y); c.y = bhi(u0.y); a23 += wv.x * c;
        c.x = blo(u0.z); c.y = bhi(u0.z); a45 += wv.x * c;
        c.x = blo(u0.w); c.y = bhi(u0.w); a67 += wv.x * c;
        c.x = blo(u1.x); c.y = bhi(u1.x); a01 += wv.y * c;
        c.x = blo(u1.y); c.y = bhi(u1.y); a23 += wv.y * c;
        c.x = blo(u1.z); c.y = bhi(u1.z); a45 += wv.y * c;
        c.x = blo(u1.w); c.y = bhi(u1.w); a67 += wv.y * c;
    }

    // combine left/right corner partials (same channels in lane li and li^4)
    a01.x += __shfl_xor(a01.x, 4); a01.y += __shfl_xor(a01.y, 4);
    a23.x += __shfl_xor(a23.x, 4); a23.y += __shfl_xor(a23.y, 4);
    a45.x += __shfl_xor(a45.x, 4); a45.y += __shfl_xor(a45.y, 4);
    a67.x += __shfl_xor(a67.x, 4); a67.y += __shfl_xor(a67.y, 4);

    // output: lane li<4 writes ch (li&3)*8 + 0..3, lane li>=4 writes +4..7
    const int hi = li >> 2;
    const float o0 = hi ? a45.x : a01.x;
    const float o1 = hi ? a45.y : a01.y;
    const float o2 = hi ? a67.x : a23.x;
    const float o3 = hi ? a67.y : a23.y;
    ushort4 o;
    o.x = f2bf(o0); o.y = f2bf(o1); o.z = f2bf(o2); o.w = f2bf(o3);
    const int d = (li & 3) * 8 + hi * 4;
    *(ushort4*)(outi + (long)bq * CDIM + h * 32 + d) = o;
}

// ---------------- launch ---------------------------------------------------
extern "C" void kernel_launch(void* const* d_in, const int* in_sizes, int n_in,
                              void* d_out, int out_size, void* d_ws, size_t ws_size,
                              hipStream_t stream) {
    const float* query     = (const float*)d_in[0];
    const float* query_pos = (const float*)d_in[1];
    const float* value     = (const float*)d_in[2];
    const float* refp      = (const float*)d_in[3];
    // d_in[4] = spatial_shapes (static, hard-coded)
    const float* W_off  = (const float*)d_in[5];
    const float* b_off  = (const float*)d_in[6];
    const float* W_attn = (const float*)d_in[7];
    const float* b_attn = (const float*)d_in[8];
    const float* W_val  = (const float*)d_in[9];
    const float* b_val  = (const float*)d_in[10];
    const float* W_out  = (const float*)d_in[11];
    const float* b_out  = (const float*)d_in[12];
    float* out = (float*)d_out;

    // workspace: all bf16 buffers as ushort
    unsigned short* v_bf = (unsigned short*)d_ws;            // 86016*256 bf16 [b][h][pos][32]
    unsigned short* q_bf = v_bf + (long)86016 * 256;         // 32768*256 bf16
    unsigned short* Wt   = q_bf + (long)32768 * 256;         // 1088*256 bf16 (transposed W's)
    float* oa_ws = (float*)(Wt + (long)1088 * 256);          // 32768*576 fp32 [off|attn]
    unsigned short* i_bf = (unsigned short*)(oa_ws + (long)32768 * 576);  // 32768*256 bf16

    const int MV = BSZ * NVAL;   // 86016
    const int MQ = BSZ * NQRY;   // 32768

    // W -> bf16 transposed
    prep_w<<<1088, 256, 0, stream>>>(W_val, W_off, W_attn, W_out, Wt);
    // q = bf16(query + query_pos)
    q_conv<<<(MQ * CDIM / 4) / 256, 256, 0, stream>>>(query, query_pos, q_bf);
    // v = value @ W_val + b_val -> bf16 [b][h][pos][32]   (A fp32 in-kernel cvt)
    gemm_mfma<256, 0, 1, 0, 0><<<dim3(1, MV / 128), 512, 0, stream>>>(
        value, Wt, b_val, nullptr, nullptr, v_bf, MV, 256);
    // [off|attn] = q @ [W_off|W_attn] + [b_off|b_attn]  (fp32 out, N=576)
    gemm_mfma<192, 1, 0, 0, 1><<<dim3(3, MQ / 128), 512, 0, stream>>>(
        q_bf, Wt + (long)256 * 256, b_off, b_attn, nullptr, oa_ws, MQ, 576);
    // deformable sampling -> interm bf16
    ms_sample4<<<MQ / 4, 256, 0, stream>>>(v_bf, oa_ws, refp, i_bf);
    // out = interm @ W_out + b_out + query
    gemm_mfma<256, 1, 0, 1, 0><<<dim3(1, MQ / 128), 512, 0, stream>>>(
        i_bf, Wt + (long)832 * 256, b_out, nullptr, query, out, MQ, 256);
}

// Round 3
// 366.693 us; speedup vs baseline: 1.1230x; 1.0746x over previous
//
#include <hip/hip_runtime.h>

// Problem constants (static per reference)
#define NHEAD 8
#define NPOINT 4
#define NLVL 6
#define CDIM 256
#define BSZ 8
#define NQRY 4096
#define NVAL 10752

typedef __attribute__((ext_vector_type(8))) short short8;   // 8 bf16 = 4 VGPRs
typedef __attribute__((ext_vector_type(4))) float floatx4;  // MFMA acc
typedef __attribute__((ext_vector_type(2))) float float2v;  // packed f32 (v_pk_fma_f32)

__device__ __forceinline__ unsigned short f2bf(float f) {
    unsigned u = __float_as_uint(f);
    return (unsigned short)((u + 0x7FFFu + ((u >> 16) & 1u)) >> 16);  // RNE
}
__device__ __forceinline__ unsigned pack2(float a, float b) {
    return (unsigned)f2bf(a) | ((unsigned)f2bf(b) << 16);
}
__device__ __forceinline__ float blo(unsigned u) { return __uint_as_float(u << 16); }
__device__ __forceinline__ float bhi(unsigned u) { return __uint_as_float(u & 0xffff0000u); }

// async global -> LDS, 16 B per lane (global_load_lds_dwordx4).
// lds dest must be wave-uniform base; HW writes base + lane*16.
__device__ __forceinline__ void gload16(const void* g, void* l) {
    __builtin_amdgcn_global_load_lds(
        (const __attribute__((address_space(1))) unsigned int*)g,
        (__attribute__((address_space(3))) unsigned int*)l, 16, 0, 0);
}

// ---- prep: W matrices -> bf16, transposed [N][256] -------------------------
// Wt rows: [0,256) = W_val^T; [256,832) = [W_off|W_attn]^T; [832,1088) = W_out^T
__global__ __launch_bounds__(256) void prep_w(
    const float* __restrict__ Wv, const float* __restrict__ Woff,
    const float* __restrict__ Wattn, const float* __restrict__ Wo,
    unsigned short* __restrict__ Wt)
{
    const int id = blockIdx.x * 256 + threadIdx.x;   // < 1088*256
    const int n = id >> 8, k = id & 255;
    float val;
    if (n < 256) val = Wv[k * 256 + n];
    else if (n < 832) {
        const int nn = n - 256;
        val = (nn < 384) ? Woff[k * 384 + nn] : Wattn[k * 192 + (nn - 384)];
    } else val = Wo[k * 256 + (n - 832)];
    Wt[id] = f2bf(val);
}

// ---- q = bf16(query + query_pos) ------------------------------------------
__global__ __launch_bounds__(256) void q_conv(
    const float* __restrict__ query, const float* __restrict__ qpos,
    unsigned short* __restrict__ qbf)
{
    const long i = ((long)blockIdx.x * 256 + threadIdx.x) * 4;
    const float4 a = *(const float4*)(query + i);
    const float4 b = *(const float4*)(qpos + i);
    ushort4 r;
    r.x = f2bf(a.x + b.x); r.y = f2bf(a.y + b.y);
    r.z = f2bf(a.z + b.z); r.w = f2bf(a.w + b.w);
    *(ushort4*)(qbf + i) = r;
}

// ---- bf16 MFMA GEMM: C[M,N] = A[M,256] @ Bt[N,256]^T + bias ---------------
// 512 thr = 8 waves; block tile 128 x BN; wave tile 64 x (BN/4).
// BK=64; LDS linear [row][64] bf16 (128 B rows), chunk-XOR swizzled:
//   phys chunk = logical chunk ^ (row & 7)   (chunk = 16 B)
// bf16 operands staged with global_load_lds dwordx4 (source pre-swizzled,
// LDS dest linear -- rule: swizzle both sides or neither). fp32 A (ABF=0)
// reg-staged + cvt, ds_write_b128 directly to swizzled address.
// ABF: A is bf16. VTRANS: C -> bf16 [b][h][pos][32]. RESID: += resid fp32.
// SPLITB: bias2 at col>=384.
template<int BN, int ABF, int VTRANS, int RESID, int SPLITB>
__global__ __launch_bounds__(512) void gemm_mfma(
    const void* __restrict__ Av, const unsigned short* __restrict__ Bt,
    const float* __restrict__ bias, const float* __restrict__ bias2,
    const float* __restrict__ resid, void* __restrict__ Cv,
    int M, int Ntot)
{
    constexpr int BK = 64, BMt = 128;
    constexpr int WN = BN / 4, NT = WN / 16;
    constexpr int ACH = BMt * (BK / 8);     // A 16B-chunks = 1024
    constexpr int BCH = BN * (BK / 8);      // B 16B-chunks
    constexpr int NCH = ACH + BCH;
    __shared__ char smem[NCH * 16];         // A: [0,16K)  B: [16K, ..)
    const int tid = threadIdx.x;
    const int bm = blockIdx.y * BMt;
    const int bcol = blockIdx.x * BN;
    const int wid = tid >> 6, lane = tid & 63;
    const int wm = (wid >> 2) * 64, wn = (wid & 3) * WN;
    const int lm = lane & 15;

    floatx4 acc[4][NT];
#pragma unroll
    for (int i = 0; i < 4; ++i)
#pragma unroll
        for (int j = 0; j < NT; ++j) acc[i][j] = (floatx4)0.0f;

    for (int k0 = 0; k0 < 256; k0 += BK) {
        if (ABF) {
            const unsigned short* A = (const unsigned short*)Av;
            constexpr int NI = NCH / 512;   // gload instrs per wave
#pragma unroll
            for (int j = 0; j < NI; ++j) {
                const int cbase = (wid * NI + j) * 64;
                const int g = cbase + lane;
                const unsigned short* src;
                if (cbase < ACH) {          // wave-uniform branch (64 | ACH)
                    const int row = g >> 3, c = (g & 7) ^ (row & 7);
                    src = A + (long)(bm + row) * 256 + k0 + c * 8;
                } else {
                    const int g2 = g - ACH;
                    const int row = g2 >> 3, c = (g2 & 7) ^ (row & 7);
                    src = Bt + (long)(bcol + row) * 256 + k0 + c * 8;
                }
                gload16(src, smem + cbase * 16);
            }
        } else {
            // B via async DMA
            constexpr int NIB = BCH / 512;
#pragma unroll
            for (int j = 0; j < NIB; ++j) {
                const int cbase = (wid * NIB + j) * 64;
                const int g2 = cbase + lane;
                const int row = g2 >> 3, c = (g2 & 7) ^ (row & 7);
                gload16(Bt + (long)(bcol + row) * 256 + k0 + c * 8,
                        smem + ACH * 16 + cbase * 16);
            }
            // A fp32 -> bf16 reg-stage (2 chunks per thread), swizzled ds_write
            const float* A = (const float*)Av;
#pragma unroll
            for (int j = 0; j < 2; ++j) {
                const int g = j * 512 + tid;
                const int row = g >> 3, c = g & 7;
                const float* p = A + (long)(bm + row) * 256 + k0 + c * 8;
                const float4 a = *(const float4*)p;
                const float4 b = *(const float4*)(p + 4);
                uint4 v;
                v.x = pack2(a.x, a.y); v.y = pack2(a.z, a.w);
                v.z = pack2(b.x, b.y); v.w = pack2(b.z, b.w);
                *(uint4*)(smem + row * 128 + ((c ^ (row & 7)) << 4)) = v;
            }
        }
        __syncthreads();

#pragma unroll
        for (int kk = 0; kk < 2; ++kk) {
            const int cc = kk * 4 + (lane >> 4);   // logical 16B chunk in row
            short8 af[4], bfr[NT];
#pragma unroll
            for (int i = 0; i < 4; ++i) {
                const int row = wm + i * 16 + lm;
                af[i] = *(const short8*)(smem + row * 128 + ((cc ^ (row & 7)) << 4));
            }
#pragma unroll
            for (int j = 0; j < NT; ++j) {
                const int row = wn + j * 16 + lm;
                bfr[j] = *(const short8*)(smem + ACH * 16 + row * 128 + ((cc ^ (row & 7)) << 4));
            }
#pragma unroll
            for (int i = 0; i < 4; ++i)
#pragma unroll
                for (int j = 0; j < NT; ++j)
                    acc[i][j] = __builtin_amdgcn_mfma_f32_16x16x32_bf16(af[i], bfr[j], acc[i][j], 0, 0, 0);
        }
        __syncthreads();
    }

    const int qrow = (lane >> 4) * 4;
#pragma unroll
    for (int j = 0; j < NT; ++j) {
        const int colg = bcol + wn + j * 16 + lm;
        const float bv = (SPLITB && colg >= 384) ? bias2[colg - 384] : bias[colg];
#pragma unroll
        for (int i = 0; i < 4; ++i) {
#pragma unroll
            for (int r = 0; r < 4; ++r) {
                const int rowl = wm + i * 16 + qrow + r;
                const int rowg = bm + rowl;
                float val = acc[i][j][r] + bv;
                if (VTRANS) {
                    // bf16 v in [b][h][pos][32]; 128 | NVAL so block is one batch
                    const int b = bm / NVAL;
                    const int pos = bm - b * NVAL + rowl;
                    const int h = colg >> 5, d = colg & 31;
                    ((unsigned short*)Cv)[(((long)(b * NHEAD + h)) * NVAL + pos) * 32 + d] = f2bf(val);
                } else {
                    if (RESID) val += resid[(long)rowg * 256 + colg];
                    ((float*)Cv)[(long)rowg * Ntot + colg] = val;
                }
            }
        }
    }
}

// ---- deformable sampling (wave per query, bf16 v, bf16 out) ----------------
// 256 thr = 4 waves = 4 queries. lane: head h = lane>>3, li = lane&7.
// v: bf16 [b][h][pos][32]; oa row: [off(384) | attn(192)] fp32.
//
// Two-phase. Phase 1: each lane owns 3 samples of its head; softmax via 8-lane
// shfl tree; per sample compute geometry ONCE and store a 24-B record
// {w0l,w1l,w0r,w1r, byteoff_row0, byteoff_row1} in LDS. The two x-corners of a
// bilinear row are adjacent 64-B blocks -> one 128-B contiguous region starting
// at xb=clamp(x0,0,W-2); corner weights re-assigned so the extra column gets 0.
// Phase 2: per (lp,row) ONE dwordx4 gather (8 lanes x 16B = 128B: lanes 0-3 =
// left corner ch li*8..+7, lanes 4-7 = right corner). Corner-side partials
// summed at the end via shfl_xor(4).
__global__ __launch_bounds__(256) void ms_sample4(
    const unsigned short* __restrict__ v,
    const float* __restrict__ oa,
    const float* __restrict__ refp,
    unsigned short* __restrict__ outi)
{
    __shared__ float s_rec[4][192 * 6];   // [wave][ (lp*8+h)*6 ] : 4x4608 B
    __shared__ float s_ref[4][12];
    const int tid = threadIdx.x;
    const int w = tid >> 6;
    const int lane = tid & 63;
    const int bq = blockIdx.x * 4 + w;
    const int b = bq >> 12;

    if (lane < 12) s_ref[w][lane] = refp[(long)bq * 12 + lane];
    __syncthreads();

    const int h = lane >> 3;
    const int li = lane & 7;
    const float* oarow = oa + (long)bq * 576;

    // ---- phase 1a: softmax over this head's 24 logits (3 per lane) --------
    const float* lgp = oarow + 384 + h * 24 + li * 3;
    const float lg0 = lgp[0], lg1 = lgp[1], lg2 = lgp[2];
    float mx = fmaxf(lg0, fmaxf(lg1, lg2));
    mx = fmaxf(mx, __shfl_xor(mx, 1));
    mx = fmaxf(mx, __shfl_xor(mx, 2));
    mx = fmaxf(mx, __shfl_xor(mx, 4));
    const float e0 = __expf(lg0 - mx);
    const float e1 = __expf(lg1 - mx);
    const float e2 = __expf(lg2 - mx);
    float den = e0 + e1 + e2;
    den += __shfl_xor(den, 1);
    den += __shfl_xor(den, 2);
    den += __shfl_xor(den, 4);
    const float inv = 1.0f / den;
    const float aw_[3] = {e0 * inv, e1 * inv, e2 * inv};

    // ---- phase 1b: geometry + fused weights for 3 owned samples -----------
    const float* offp = oarow + (h * 24 + li * 3) * 2;   // 8-B aligned
    const float2v od0 = *(const float2v*)(offp);
    const float2v od1 = *(const float2v*)(offp + 2);
    const float2v od2 = *(const float2v*)(offp + 4);

#pragma unroll
    for (int k = 0; k < 3; ++k) {
        const int lp = li * 3 + k;
        const int l = lp >> 2;
        const int sh = (l >= 3) ? (l - 3) : l;
        const int W = 64 >> sh;
        const int base = ((l >= 3) ? 5376 : 0)
                       + ((sh >= 1) ? 4096 : 0)
                       + ((sh >= 2) ? 1024 : 0);
        const float Wf = (float)W;
        const float ox = (k == 0) ? od0.x : (k == 1) ? od1.x : od2.x;
        const float oy = (k == 0) ? od0.y : (k == 1) ? od1.y : od2.y;
        const float rx = s_ref[w][l * 2 + 0];
        const float ry = s_ref[w][l * 2 + 1];
        const float x = rx * Wf + ox - 0.5f;   // == ((rx + ox/W)*W - 0.5), pow2
        const float y = ry * Wf + oy - 0.5f;
        const float xf = floorf(x), yf = floorf(y);
        const int x0 = (int)xf, y0 = (int)yf;
        const float lx = x - xf, ly = y - yf;
        const float wx0 = (x0 >= 0 && x0 < W)      ? (1.f - lx) : 0.f;
        const float wx1 = (x0 >= -1 && x0 < W - 1) ? lx         : 0.f;
        const float wy0 = (y0 >= 0 && y0 < W)      ? (1.f - ly) : 0.f;
        const float wy1 = (y0 >= -1 && y0 < W - 1) ? ly         : 0.f;
        const int y0c = min(max(y0, 0), W - 1);
        const int y1c = min(max(y0 + 1, 0), W - 1);
        // x: load 128-B region [xb, xb+1]; re-assign corner weights so the
        // padded column carries weight 0 (OOB corners have wx==0 already).
        const int xb = min(max(x0, 0), W - 2);
        const float wl = (xb == x0) ? wx0 : ((xb == x0 + 1) ? wx1 : 0.f);
        const float wr = (xb == x0) ? wx1 : ((xb == x0 - 1) ? wx0 : 0.f);
        const float aw = aw_[k];
        const float awl = aw * wl, awr = aw * wr;
        float* r = &s_rec[w][((lp << 3) + h) * 6];
        float2v wlv, wrv;
        wlv.x = awl * wy0; wlv.y = awl * wy1;   // (row0, row1) left corner
        wrv.x = awr * wy0; wrv.y = awr * wy1;   // (row0, row1) right corner
        *(float2v*)(r)     = wlv;
        *(float2v*)(r + 2) = wrv;
        uint2 pk;
        pk.x = (unsigned)(base + y0c * W + xb) * 64u;   // byte offset, row0
        pk.y = (unsigned)(base + y1c * W + xb) * 64u;   // byte offset, row1
        *(uint2*)(r + 4) = pk;
    }
    __syncthreads();

    // ---- phase 2: gather + accumulate (packed f32) ------------------------
    // lane carries 8 channels [(li&3)*8 .. +7] of ONE corner side (li<4 left).
    const unsigned lane_base =
        (unsigned)((b * NHEAD + h) * NVAL) * 64u + (unsigned)li * 16u;
    const char* vbase = (const char*)v;
    const int sel = (li >> 2) * 2;            // weight pair: 0=left, 2=right
    const float* rp0 = &s_rec[w][h * 6];
    float2v a01 = {0.f, 0.f}, a23 = {0.f, 0.f};
    float2v a45 = {0.f, 0.f}, a67 = {0.f, 0.f};

#pragma unroll 8
    for (int lp = 0; lp < NLVL * NPOINT; ++lp) {
        const float* rp = rp0 + lp * 48;
        const float2v wv = *(const float2v*)(rp + sel);   // (w_row0, w_row1)
        const uint2 off = *(const uint2*)(rp + 4);
        const uint4 u0 = *(const uint4*)(vbase + (lane_base + off.x));
        const uint4 u1 = *(const uint4*)(vbase + (lane_base + off.y));
        float2v c;
        c.x = blo(u0.x); c.y = bhi(u0.x); a01 += wv.x * c;
        c.x = blo(u0.y); c.y = bhi(u0.y); a23 += wv.x * c;
        c.x = blo(u0.z); c.y = bhi(u0.z); a45 += wv.x * c;
        c.x = blo(u0.w); c.y = bhi(u0.w); a67 += wv.x * c;
        c.x = blo(u1.x); c.y = bhi(u1.x); a01 += wv.y * c;
        c.x = blo(u1.y); c.y = bhi(u1.y); a23 += wv.y * c;
        c.x = blo(u1.z); c.y = bhi(u1.z); a45 += wv.y * c;
        c.x = blo(u1.w); c.y = bhi(u1.w); a67 += wv.y * c;
    }

    // combine left/right corner partials (same channels in lane li and li^4)
    a01.x += __shfl_xor(a01.x, 4); a01.y += __shfl_xor(a01.y, 4);
    a23.x += __shfl_xor(a23.x, 4); a23.y += __shfl_xor(a23.y, 4);
    a45.x += __shfl_xor(a45.x, 4); a45.y += __shfl_xor(a45.y, 4);
    a67.x += __shfl_xor(a67.x, 4); a67.y += __shfl_xor(a67.y, 4);

    // output: lane li<4 writes ch (li&3)*8 + 0..3, lane li>=4 writes +4..7
    const int hi = li >> 2;
    const float o0 = hi ? a45.x : a01.x;
    const float o1 = hi ? a45.y : a01.y;
    const float o2 = hi ? a67.x : a23.x;
    const float o3 = hi ? a67.y : a23.y;
    ushort4 o;
    o.x = f2bf(o0); o.y = f2bf(o1); o.z = f2bf(o2); o.w = f2bf(o3);
    const int d = (li & 3) * 8 + hi * 4;
    *(ushort4*)(outi + (long)bq * CDIM + h * 32 + d) = o;
}

// ---------------- launch ---------------------------------------------------
extern "C" void kernel_launch(void* const* d_in, const int* in_sizes, int n_in,
                              void* d_out, int out_size, void* d_ws, size_t ws_size,
                              hipStream_t stream) {
    const float* query     = (const float*)d_in[0];
    const float* query_pos = (const float*)d_in[1];
    const float* value     = (const float*)d_in[2];
    const float* refp      = (const float*)d_in[3];
    // d_in[4] = spatial_shapes (static, hard-coded)
    const float* W_off  = (const float*)d_in[5];
    const float* b_off  = (const float*)d_in[6];
    const float* W_attn = (const float*)d_in[7];
    const float* b_attn = (const float*)d_in[8];
    const float* W_val  = (const float*)d_in[9];
    const float* b_val  = (const float*)d_in[10];
    const float* W_out  = (const float*)d_in[11];
    const float* b_out  = (const float*)d_in[12];
    float* out = (float*)d_out;

    // workspace: all bf16 buffers as ushort
    unsigned short* v_bf = (unsigned short*)d_ws;            // 86016*256 bf16 [b][h][pos][32]
    unsigned short* q_bf = v_bf + (long)86016 * 256;         // 32768*256 bf16
    unsigned short* Wt   = q_bf + (long)32768 * 256;         // 1088*256 bf16 (transposed W's)
    float* oa_ws = (float*)(Wt + (long)1088 * 256);          // 32768*576 fp32 [off|attn]
    unsigned short* i_bf = (unsigned short*)(oa_ws + (long)32768 * 576);  // 32768*256 bf16

    const int MV = BSZ * NVAL;   // 86016
    const int MQ = BSZ * NQRY;   // 32768

    // W -> bf16 transposed
    prep_w<<<1088, 256, 0, stream>>>(W_val, W_off, W_attn, W_out, Wt);
    // q = bf16(query + query_pos)
    q_conv<<<(MQ * CDIM / 4) / 256, 256, 0, stream>>>(query, query_pos, q_bf);
    // v = value @ W_val + b_val -> bf16 [b][h][pos][32]   (A fp32 in-kernel cvt)
    gemm_mfma<256, 0, 1, 0, 0><<<dim3(1, MV / 128), 512, 0, stream>>>(
        value, Wt, b_val, nullptr, nullptr, v_bf, MV, 256);
    // [off|attn] = q @ [W_off|W_attn] + [b_off|b_attn]  (fp32 out, N=576)
    gemm_mfma<192, 1, 0, 0, 1><<<dim3(3, MQ / 128), 512, 0, stream>>>(
        q_bf, Wt + (long)256 * 256, b_off, b_attn, nullptr, oa_ws, MQ, 576);
    // deformable sampling -> interm bf16
    ms_sample4<<<MQ / 4, 256, 0, stream>>>(v_bf, oa_ws, refp, i_bf);
    // out = interm @ W_out + b_out + query
    gemm_mfma<256, 1, 0, 1, 0><<<dim3(1, MQ / 128), 512, 0, stream>>>(
        i_bf, Wt + (long)832 * 256, b_out, nullptr, query, out, MQ, 256);
}